// Round 13
// baseline (52.237 us; speedup 1.0000x reference)
//
#include <hip/hip_runtime.h>
#include <hip/hip_bf16.h>

#define NBS 8
#define NT 32
#define NF 128
#define NDIN 64
#define NNH 8
#define NDOUT 64

typedef __bf16 bf16_t;
typedef __bf16 bf16x8 __attribute__((ext_vector_type(8)));
typedef float f32x4 __attribute__((ext_vector_type(4)));
typedef float f32x2 __attribute__((ext_vector_type(2)));

// ---------------- kernel 1: q/k projection ----------------
// One wave per (t,f): q[b,he] = sum_d X[b,f,t,d] * Wq[t,f,d,he], all 8 b at once.
// Wq/Wk/X each read exactly once from HBM -> ~46MB -> memory-bound ~8us.
__global__ __launch_bounds__(256, 4)
void qk_project_kernel(const float* __restrict__ X,
                       const float* __restrict__ Wq,
                       const float* __restrict__ Wk,
                       float* __restrict__ q_ws,
                       float* __restrict__ k_ws)
{
    __shared__ float lx[4][8][64];
    const int w = threadIdx.x >> 6, lane = threadIdx.x & 63;
    const int gw = blockIdx.x * 4 + w;
    const int t = gw >> 7, f = gw & 127;

    {
        const int b = lane >> 3, d8 = (lane & 7) << 3;
        const float* src = &X[(((size_t)b * NF + f) * NT + t) * NDIN + d8];
        const float4 v0 = *(const float4*)src;
        const float4 v1 = *(const float4*)(src + 4);
        *(float4*)&lx[w][b][d8]     = v0;
        *(float4*)&lx[w][b][d8 + 4] = v1;
    }
    __syncthreads();

    const int dq = lane >> 4, he = lane & 15;
    const float* wq = Wq + ((size_t)t * NF + f) * (NDIN * 16);
    const float* wk = Wk + ((size_t)t * NF + f) * (NDIN * 16);
    float qa[8] = {0,0,0,0,0,0,0,0}, ka[8] = {0,0,0,0,0,0,0,0};
    for (int d0 = 0; d0 < NDIN; d0 += 4) {
        const int d = d0 + dq;
        const float wqv = wq[d * 16 + he];
        const float wkv = wk[d * 16 + he];
#pragma unroll
        for (int b = 0; b < 8; ++b) {
            const float x = lx[w][b][d];
            qa[b] = fmaf(x, wqv, qa[b]);
            ka[b] = fmaf(x, wkv, ka[b]);
        }
    }
#pragma unroll
    for (int b = 0; b < 8; ++b) {
        qa[b] += __shfl_xor(qa[b], 16); qa[b] += __shfl_xor(qa[b], 32);
        ka[b] += __shfl_xor(ka[b], 16); ka[b] += __shfl_xor(ka[b], 32);
    }
#pragma unroll
    for (int bb = 0; bb < 2; ++bb) {
        const int b = dq + bb * 4;
        q_ws[(((size_t)b * NT + t) * 16 + he) * NF + f] = qa[b];
        k_ws[(((size_t)b * NT + t) * 16 + he) * NF + f] = ka[b];
    }
}

// ---------------- kernel 2: attention + output GEMMs ----------------
// r12 structure (one block per (b,t), 512 thr = 8 waves, wave = row-tile,
// 8 heads/wave, swizzled XT/WT, pk-f32 scores) with LDS cut 140KB -> 74KB
// so TWO blocks fit per CU (4 waves/SIMD; r12 measured 17% occupancy = the
// dominant stall):
//  (1) WTall upfront (64KB) -> per-head double-buffered WT (2x8KB), r7-proven
//      pattern: stage head th+1 into alt buffer during head th, barrier at
//      iteration end.
//  (2) kvf dedup: u is h-independent -> kvu[64] (1KB) + kvh[8][64] (8KB).
// LAUNCH BOUNDS RULE (r4/r5/r8): 2nd arg >=4 forces the 64-VGPR bucket and
// 300MB of scratch spills; (512,2) is the proven-safe bound. VGPR must stay
// <=128 for the 2nd block (m69: waves/SIMD halve at 64/128/256).
__global__ __launch_bounds__(512, 2)
void spatial_attn_kernel(const float* __restrict__ X,
                         const float* __restrict__ q_ws,
                         const float* __restrict__ k_ws,
                         const float* __restrict__ Wkey,
                         const float* __restrict__ U,
                         const float* __restrict__ AC,
                         const float* __restrict__ Alpha,
                         const float* __restrict__ Wo,
                         const float* __restrict__ Bias,
                         float* __restrict__ Out)
{
    const int blk  = blockIdx.x;
    const int b    = blk & 7;
    const int t    = blk >> 3;
    const int tid  = threadIdx.x;
    const int w    = tid >> 6;
    const int lane = tid & 63;
    const int cq   = lane & 15;
    const int rq   = lane >> 4;
    const int rt   = w;                // row tile 0..7
    const int frow = 16 * rt + cq;

    // LDS carve: 75776 B (2 blocks/CU = 151552 <= 163840)
    __shared__ __align__(16) unsigned char smem[75776];
    bf16_t* XTs   = (bf16_t*)smem;                        // 16384: d*128 + (((f>>3)^(d&15))<<3) + (f&7)
    float*  kvh   = (float*)(smem + 16384);               //  8192: (h*64+P)*4 + {k0k0, k1k1}
    float*  kvu   = (float*)(smem + 24576);               //  1024: P*4 + {u0u0, u1u1}
    float4 (*qf)[128] = (float4 (*)[128])(smem + 25600);  // 16384: {q0,q1,kf0,kf1}(h,f)
    bf16_t* WTs   = (bf16_t*)(smem + 41984);              // 16384: buf*4096 + o*64 + (((d>>3)^(o&7))<<3) + (d&7)
    bf16_t (*Vscr)[16][68] = (bf16_t (*)[16][68])(smem + 58368); // 17408

    // ---- stage XT (X^T bf16, XOR-swizzled; r12-verbatim) ----
#pragma unroll
    for (int r = 0; r < 4; ++r) {
        const int idx = tid + r * 512;
        const int f = idx >> 4, d4 = (idx & 15) << 2;
        const float4 v = *(const float4*)&X[(((size_t)b * NF + f) * NT + t) * NDIN + d4];
        float vv[4]; vv[0] = v.x; vv[1] = v.y; vv[2] = v.z; vv[3] = v.w;
#pragma unroll
        for (int i = 0; i < 4; ++i) {
            const int d = d4 + i;
            XTs[d * 128 + (((f >> 3) ^ (d & 15)) << 3) + (f & 7)] = (bf16_t)vv[i];
        }
    }
    // ---- stage qf + kvh: one thread per (h,l), 2 reps ----
#pragma unroll
    for (int r = 0; r < 2; ++r) {
        const int idx = tid + r * 512;
        const int hh = idx >> 7, l = idx & 127;
        const size_t qkb = ((size_t)b * NT + t) * 16;
        const float k0 = k_ws[(qkb + 2 * hh + 0) * NF + l];
        const float k1 = k_ws[(qkb + 2 * hh + 1) * NF + l];
        const float q0 = q_ws[(qkb + 2 * hh + 0) * NF + l];
        const float q1 = q_ws[(qkb + 2 * hh + 1) * NF + l];
        qf[hh][l] = make_float4(q0, q1, k0, k1);
        const int P = l >> 1, c = l & 1;
        const int base = (hh * 64 + P) * 4;
        kvh[base + 0 + c] = k0;
        kvh[base + 2 + c] = k1;
    }
    // ---- stage kvu (h-independent) ----
    if (tid < 128) {
        const int l = tid;
        const float2 u01 = *(const float2*)&U[((size_t)t * NF + l) * 2];
        const int P = l >> 1, c = l & 1;
        kvu[P * 4 + 0 + c] = u01.x;
        kvu[P * 4 + 2 + c] = u01.y;
    }
    // ---- stage WT for head 0 into buf 0 (swizzled) ----
#pragma unroll
    for (int r = 0; r < 2; ++r) {
        const int idx = tid + r * 512;
        const int dd = idx >> 4, o4 = (idx & 15) << 2;
        const float4 v = *(const float4*)&Wo[((size_t)t * 512 + dd) * NDOUT + o4];
        float vv[4]; vv[0] = v.x; vv[1] = v.y; vv[2] = v.z; vv[3] = v.w;
#pragma unroll
        for (int i = 0; i < 4; ++i) {
            const int o = o4 + i;
            WTs[o * 64 + (((dd >> 3) ^ (o & 7)) << 3) + (dd & 7)] = (bf16_t)vv[i];
        }
    }

    const float alpha_t = Alpha[t];
    const float wk00 = Wkey[t * 4 + 0], wk01 = Wkey[t * 4 + 1];
    const float wk10 = Wkey[t * 4 + 2], wk11 = Wkey[t * 4 + 3];

    __syncthreads();   // staging complete (incl. WT buf 0)

    f32x4 oacc[4] = { {0.f,0.f,0.f,0.f}, {0.f,0.f,0.f,0.f}, {0.f,0.f,0.f,0.f}, {0.f,0.f,0.f,0.f} };

#pragma unroll 1
    for (int h = 0; h < NNH; ++h) {
        // stage WT for h+1 into the alternate buffer (disjoint from reads of buf h&1)
        if (h < 7) {
            const int bn = ((h + 1) & 1) * 4096;
#pragma unroll
            for (int r = 0; r < 2; ++r) {
                const int idx = tid + r * 512;
                const int dd = idx >> 4, o4 = (idx & 15) << 2;
                const float4 v = *(const float4*)&Wo[((size_t)t * 512 + (h + 1) * 64 + dd) * NDOUT + o4];
                float vv[4]; vv[0] = v.x; vv[1] = v.y; vv[2] = v.z; vv[3] = v.w;
#pragma unroll
                for (int i = 0; i < 4; ++i) {
                    const int o = o4 + i;
                    WTs[bn + o * 64 + (((dd >> 3) ^ (o & 7)) << 3) + (dd & 7)] = (bf16_t)vv[i];
                }
            }
        }
        const int buf = (h & 1) * 4096;
        const float4 qq = qf[h][frow];             // {q0,q1,kf0,kf1}
        const float q0 = qq.x, q1 = qq.y, kf0 = qq.z, kf1 = qq.w;
        const float v1 = 2.f * alpha_t * AC[t * NNH + h];
        const float c0 = (q0 - alpha_t) * wk00 + (q1 + v1) * wk10;
        const float c1 = (q0 - alpha_t) * wk01 + (q1 + v1) * wk11;

        // ---- scores, packed float2 over l-pairs (r12-verbatim math) ----
        f32x2 sc2[4][4];
        f32x2 mx2 = { -3.0e38f, -3.0e38f };
#pragma unroll
        for (int kt = 0; kt < 4; ++kt) {
#pragma unroll
            for (int j2 = 0; j2 < 4; ++j2) {
                const int P = kt * 16 + rq * 4 + j2;
                const float4 kp = *(const float4*)&kvh[(h * 64 + P) * 4];
                const float4 up = *(const float4*)&kvu[P * 4];
                const f32x2 k0p = { kp.x, kp.y };
                const f32x2 k1p = { kp.z, kp.w };
                const f32x2 u0p = { up.x, up.y };
                const f32x2 u1p = { up.z, up.w };
                const float l0 = (float)(kt * 32 + rq * 8 + 2 * j2 - frow);
                const f32x2 delp = { l0, l0 + 1.f };
                f32x2 sv = k0p * q0 + k1p * q1 + u0p * kf0 + u1p * kf1
                         + (delp * c0 + c1) * delp;
                sc2[kt][j2] = sv;
                mx2 = __builtin_elementwise_max(mx2, sv);
            }
        }
        float rowmax = fmaxf(mx2.x, mx2.y);
        rowmax = fmaxf(rowmax, __shfl_xor(rowmax, 16));
        rowmax = fmaxf(rowmax, __shfl_xor(rowmax, 32));
        f32x2 s2 = { 0.f, 0.f };
#pragma unroll
        for (int kt = 0; kt < 4; ++kt)
#pragma unroll
            for (int j2 = 0; j2 < 4; ++j2) {
                f32x2 sv = sc2[kt][j2];
                const f32x2 e = { __expf(sv.x - rowmax), __expf(sv.y - rowmax) };
                s2 += e;
                sc2[kt][j2] = e;
            }
        float sum = s2.x + s2.y;
        sum += __shfl_xor(sum, 16);
        sum += __shfl_xor(sum, 32);
        const float rinv = 1.f / sum;

        // ---- GEMM1: V[16x64] = P[16x128] @ X[128x64]; P normalized pre-MFMA ----
        f32x4 vacc[4] = { {0.f,0.f,0.f,0.f}, {0.f,0.f,0.f,0.f}, {0.f,0.f,0.f,0.f}, {0.f,0.f,0.f,0.f} };
#pragma unroll
        for (int kt = 0; kt < 4; ++kt) {
            bf16x8 pf;
#pragma unroll
            for (int j2 = 0; j2 < 4; ++j2) {
                const f32x2 e = sc2[kt][j2];
                pf[2 * j2 + 0] = (bf16_t)(e.x * rinv);
                pf[2 * j2 + 1] = (bf16_t)(e.y * rinv);
            }
#pragma unroll
            for (int ct = 0; ct < 4; ++ct) {
                const bf16x8 bb = *(const bf16x8*)&XTs[(ct * 16 + cq) * 128 + (((kt * 4 + rq) ^ cq) << 3)];
                vacc[ct] = __builtin_amdgcn_mfma_f32_16x16x32_bf16(pf, bb, vacc[ct], 0, 0, 0);
            }
        }
        // V C-frags -> private wave scratch (intra-wave dep only, no barrier)
#pragma unroll
        for (int ct = 0; ct < 4; ++ct)
#pragma unroll
            for (int rr = 0; rr < 4; ++rr)
                Vscr[w][rq * 4 + rr][ct * 16 + cq] = (bf16_t)vacc[ct][rr];

        // ---- GEMM2: oacc += V[16x64] @ W_h[64x64] ----
#pragma unroll
        for (int kt = 0; kt < 2; ++kt) {
            const bf16x8 a = *(const bf16x8*)&Vscr[w][cq][kt * 32 + rq * 8];
#pragma unroll
            for (int ct = 0; ct < 4; ++ct) {
                const bf16x8 bw = *(const bf16x8*)&WTs[buf + (ct * 16 + cq) * 64 + (((kt * 4 + rq) ^ (cq & 7)) << 3)];
                oacc[ct] = __builtin_amdgcn_mfma_f32_16x16x32_bf16(a, bw, oacc[ct], 0, 0, 0);
            }
        }
        __syncthreads();   // next head's WT buffer ready; this buffer free for h+2
    }

    // ---- epilogue: Out = oacc + bias (all 8 heads complete per wave) ----
#pragma unroll
    for (int ct = 0; ct < 4; ++ct) {
#pragma unroll
        for (int rr = 0; rr < 4; ++rr) {
            const int f = 16 * rt + rq * 4 + rr;
            const int o = ct * 16 + cq;
            Out[(((size_t)b * NF + f) * NT + t) * NDOUT + o] =
                oacc[ct][rr] + Bias[((size_t)f * NT + t) * NDOUT + o];
        }
    }
}

extern "C" void kernel_launch(void* const* d_in, const int* in_sizes, int n_in,
                              void* d_out, int out_size, void* d_ws, size_t ws_size,
                              hipStream_t stream) {
    (void)in_sizes; (void)n_in; (void)ws_size; (void)out_size;
    const float* X    = (const float*)d_in[0];
    const float* Wq   = (const float*)d_in[1];
    const float* Wk   = (const float*)d_in[2];
    const float* Wkey = (const float*)d_in[3];
    const float* U    = (const float*)d_in[4];
    const float* AC   = (const float*)d_in[5];
    const float* Al   = (const float*)d_in[6];
    // d_in[7] = R is analytic (delta^2, delta), folded into score formula
    const float* Wo   = (const float*)d_in[8];
    const float* Bias = (const float*)d_in[9];

    float* q_ws = (float*)d_ws;                       // 2 MB
    float* k_ws = q_ws + (size_t)NBS * NT * 16 * NF;  // 2 MB

    qk_project_kernel<<<dim3(NT * NF / 4), dim3(256), 0, stream>>>(X, Wq, Wk, q_ws, k_ws);
    spatial_attn_kernel<<<dim3(NBS * NT), dim3(512), 0, stream>>>(
        X, q_ws, k_ws, Wkey, U, AC, Al, Wo, Bias, (float*)d_out);
}

// Round 14
// 49.153 us; speedup vs baseline: 1.0627x; 1.0627x over previous
//
#include <hip/hip_runtime.h>
#include <hip/hip_bf16.h>

#define NBS 8
#define NT 32
#define NF 128
#define NDIN 64
#define NNH 8
#define NDOUT 64

typedef __bf16 bf16_t;
typedef __bf16 bf16x8 __attribute__((ext_vector_type(8)));
typedef float f32x4 __attribute__((ext_vector_type(4)));
typedef float f32x2 __attribute__((ext_vector_type(2)));

// ---------------- kernel 1: q/k projection ----------------
// One wave per (t,f): q[b,he] = sum_d X[b,f,t,d] * Wq[t,f,d,he], all 8 b at once.
// Wq/Wk/X each read exactly once from HBM -> ~46MB -> memory-bound, ~6us measured.
__global__ __launch_bounds__(256, 4)
void qk_project_kernel(const float* __restrict__ X,
                       const float* __restrict__ Wq,
                       const float* __restrict__ Wk,
                       float* __restrict__ q_ws,
                       float* __restrict__ k_ws)
{
    __shared__ float lx[4][8][64];
    const int w = threadIdx.x >> 6, lane = threadIdx.x & 63;
    const int gw = blockIdx.x * 4 + w;
    const int t = gw >> 7, f = gw & 127;

    {
        const int b = lane >> 3, d8 = (lane & 7) << 3;
        const float* src = &X[(((size_t)b * NF + f) * NT + t) * NDIN + d8];
        const float4 v0 = *(const float4*)src;
        const float4 v1 = *(const float4*)(src + 4);
        *(float4*)&lx[w][b][d8]     = v0;
        *(float4*)&lx[w][b][d8 + 4] = v1;
    }
    __syncthreads();

    const int dq = lane >> 4, he = lane & 15;
    const float* wq = Wq + ((size_t)t * NF + f) * (NDIN * 16);
    const float* wk = Wk + ((size_t)t * NF + f) * (NDIN * 16);
    float qa[8] = {0,0,0,0,0,0,0,0}, ka[8] = {0,0,0,0,0,0,0,0};
    for (int d0 = 0; d0 < NDIN; d0 += 4) {
        const int d = d0 + dq;
        const float wqv = wq[d * 16 + he];
        const float wkv = wk[d * 16 + he];
#pragma unroll
        for (int b = 0; b < 8; ++b) {
            const float x = lx[w][b][d];
            qa[b] = fmaf(x, wqv, qa[b]);
            ka[b] = fmaf(x, wkv, ka[b]);
        }
    }
#pragma unroll
    for (int b = 0; b < 8; ++b) {
        qa[b] += __shfl_xor(qa[b], 16); qa[b] += __shfl_xor(qa[b], 32);
        ka[b] += __shfl_xor(ka[b], 16); ka[b] += __shfl_xor(ka[b], 32);
    }
#pragma unroll
    for (int bb = 0; bb < 2; ++bb) {
        const int b = dq + bb * 4;
        q_ws[(((size_t)b * NT + t) * 16 + he) * NF + f] = qa[b];
        k_ws[(((size_t)b * NT + t) * 16 + he) * NF + f] = ka[b];
    }
}

// ---------------- kernel 2: attention + output GEMMs ----------------
// Base = r12 winner (49.0us): one block per (b,t), 512 thr = 8 waves, wave =
// row-tile, 8 heads/wave, swizzled XT/WTall (staged upfront), pk-f32 scores,
// ONE barrier. Round-14 delta: 2-HEAD SOFTWARE PIPELINE — head h+1's
// score/exp/reduce VALU chain sits in the same basic block as head h's
// GEMM1/GEMM2 MFMA chain (separate HW pipes, m114) so the scheduler can
// interleave them. pA/pB named buffers, manual x2 unroll (rule #20: no
// runtime-indexed register arrays). Register pressure is FREE here: grid =
// 256 blocks = 1 block/CU always -> occupancy is grid-capped at 8 waves/CU
// (2/SIMD), which only needs <=256 VGPR. (r13 lesson: LDS/VGPR dieting
// cannot raise occupancy when the grid has nothing else to schedule.)
// LAUNCH BOUNDS RULE (r4/r5/r8): 2nd arg >=4 forces the 64-VGPR bucket and
// 300MB of scratch spills; (512,2) is the proven-safe bound.
__global__ __launch_bounds__(512, 2)
void spatial_attn_kernel(const float* __restrict__ X,
                         const float* __restrict__ q_ws,
                         const float* __restrict__ k_ws,
                         const float* __restrict__ Wkey,
                         const float* __restrict__ U,
                         const float* __restrict__ AC,
                         const float* __restrict__ Alpha,
                         const float* __restrict__ Wo,
                         const float* __restrict__ Bias,
                         float* __restrict__ Out)
{
    const int blk  = blockIdx.x;
    const int b    = blk & 7;
    const int t    = blk >> 3;
    const int tid  = threadIdx.x;
    const int w    = tid >> 6;
    const int lane = tid & 63;
    const int cq   = lane & 15;
    const int rq   = lane >> 4;
    const int rt   = w;                // row tile 0..7
    const int frow = 16 * rt + cq;

    // LDS carve: 140288 B (<= 160 KiB; grid caps us at 1 block/CU anyway)
    __shared__ __align__(16) unsigned char smem[140288];
    bf16_t* XTs   = (bf16_t*)smem;                    // 16384: d*128 + (((f>>3)^(d&15))<<3) + (f&7)
    float*  kvf   = (float*)(smem + 16384);           // 24576: pair P of l: (h*64+P)*12 + {k0k0,k1k1,u0u0,u1u1,pad}
    float4 (*qf)[128] = (float4 (*)[128])(smem + 40960); // 16384: {q0,q1,kf0,kf1}(h,f)
    bf16_t* WTall = (bf16_t*)(smem + 57344);          // 65536: h*4096 + o*64 + (((d>>3)^(o&7))<<3) + (d&7)
    bf16_t (*Vscr)[16][68] = (bf16_t (*)[16][68])(smem + 122880); // 17408

    // ---- stage XT (X^T bf16, XOR-swizzled; r12-verbatim) ----
#pragma unroll
    for (int r = 0; r < 4; ++r) {
        const int idx = tid + r * 512;
        const int f = idx >> 4, d4 = (idx & 15) << 2;
        const float4 v = *(const float4*)&X[(((size_t)b * NF + f) * NT + t) * NDIN + d4];
        float vv[4]; vv[0] = v.x; vv[1] = v.y; vv[2] = v.z; vv[3] = v.w;
#pragma unroll
        for (int i = 0; i < 4; ++i) {
            const int d = d4 + i;
            XTs[d * 128 + (((f >> 3) ^ (d & 15)) << 3) + (f & 7)] = (bf16_t)vv[i];
        }
    }
    // ---- stage qf + kvf: one thread per (h,l), 2 reps ----
#pragma unroll
    for (int r = 0; r < 2; ++r) {
        const int idx = tid + r * 512;
        const int hh = idx >> 7, l = idx & 127;
        const size_t qkb = ((size_t)b * NT + t) * 16;
        const float k0 = k_ws[(qkb + 2 * hh + 0) * NF + l];
        const float k1 = k_ws[(qkb + 2 * hh + 1) * NF + l];
        const float q0 = q_ws[(qkb + 2 * hh + 0) * NF + l];
        const float q1 = q_ws[(qkb + 2 * hh + 1) * NF + l];
        const float2 u01 = *(const float2*)&U[((size_t)t * NF + l) * 2];
        qf[hh][l] = make_float4(q0, q1, k0, k1);
        const int P = l >> 1, c = l & 1;
        const int base = (hh * 64 + P) * 12;
        kvf[base + 0 + c] = k0;
        kvf[base + 2 + c] = k1;
        kvf[base + 4 + c] = u01.x;
        kvf[base + 6 + c] = u01.y;
    }
    // ---- stage WTall[h] (bf16, XOR-swizzled; r12-verbatim) ----
#pragma unroll
    for (int rep = 0; rep < 16; ++rep) {
        const int flat = rep * 512 + tid;              // 0..8191
        const int h = flat >> 10, f10 = flat & 1023;
        const int dd = f10 >> 4, o4 = (f10 & 15) << 2;
        const float4 v = *(const float4*)&Wo[((size_t)t * 512 + h * 64 + dd) * NDOUT + o4];
        float vv[4]; vv[0] = v.x; vv[1] = v.y; vv[2] = v.z; vv[3] = v.w;
#pragma unroll
        for (int i = 0; i < 4; ++i) {
            const int o = o4 + i;
            WTall[h * 4096 + o * 64 + (((dd >> 3) ^ (o & 7)) << 3) + (dd & 7)] = (bf16_t)vv[i];
        }
    }

    const float alpha_t = Alpha[t];
    const float wk00 = Wkey[t * 4 + 0], wk01 = Wkey[t * 4 + 1];
    const float wk10 = Wkey[t * 4 + 2], wk11 = Wkey[t * 4 + 3];

    __syncthreads();   // the ONLY barrier

    f32x4 oacc[4] = { {0.f,0.f,0.f,0.f}, {0.f,0.f,0.f,0.f}, {0.f,0.f,0.f,0.f}, {0.f,0.f,0.f,0.f} };

    // scores+softmax for head hn -> normalized P fragments (r12-verbatim math)
    auto compute_pf = [&](const int hn, bf16x8* pf) {
        const float4 qq = qf[hn][frow];             // {q0,q1,kf0,kf1}
        const float q0 = qq.x, q1 = qq.y, kf0 = qq.z, kf1 = qq.w;
        const float v1 = 2.f * alpha_t * AC[t * NNH + hn];
        const float c0 = (q0 - alpha_t) * wk00 + (q1 + v1) * wk10;
        const float c1 = (q0 - alpha_t) * wk01 + (q1 + v1) * wk11;
        f32x2 sc2[4][4];
        f32x2 mx2 = { -3.0e38f, -3.0e38f };
#pragma unroll
        for (int kt = 0; kt < 4; ++kt) {
#pragma unroll
            for (int j2 = 0; j2 < 4; ++j2) {
                const int P = kt * 16 + rq * 4 + j2;
                const float4 ld0 = *(const float4*)&kvf[(hn * 64 + P) * 12];
                const float4 ld1 = *(const float4*)&kvf[(hn * 64 + P) * 12 + 4];
                const f32x2 k0p = { ld0.x, ld0.y };
                const f32x2 k1p = { ld0.z, ld0.w };
                const f32x2 u0p = { ld1.x, ld1.y };
                const f32x2 u1p = { ld1.z, ld1.w };
                const float l0 = (float)(kt * 32 + rq * 8 + 2 * j2 - frow);
                const f32x2 delp = { l0, l0 + 1.f };
                f32x2 sv = k0p * q0 + k1p * q1 + u0p * kf0 + u1p * kf1
                         + (delp * c0 + c1) * delp;
                sc2[kt][j2] = sv;
                mx2 = __builtin_elementwise_max(mx2, sv);
            }
        }
        float rowmax = fmaxf(mx2.x, mx2.y);
        rowmax = fmaxf(rowmax, __shfl_xor(rowmax, 16));
        rowmax = fmaxf(rowmax, __shfl_xor(rowmax, 32));
        f32x2 s2 = { 0.f, 0.f };
#pragma unroll
        for (int kt = 0; kt < 4; ++kt)
#pragma unroll
            for (int j2 = 0; j2 < 4; ++j2) {
                f32x2 sv = sc2[kt][j2];
                const f32x2 e = { __expf(sv.x - rowmax), __expf(sv.y - rowmax) };
                s2 += e;
                sc2[kt][j2] = e;
            }
        float sum = s2.x + s2.y;
        sum += __shfl_xor(sum, 16);
        sum += __shfl_xor(sum, 32);
        const float rinv = 1.f / sum;
#pragma unroll
        for (int kt = 0; kt < 4; ++kt) {
#pragma unroll
            for (int j2 = 0; j2 < 4; ++j2) {
                const f32x2 e = sc2[kt][j2];
                pf[kt][2 * j2 + 0] = (bf16_t)(e.x * rinv);
                pf[kt][2 * j2 + 1] = (bf16_t)(e.y * rinv);
            }
        }
    };

    // GEMM1 + Vscr + GEMM2 for head hn using P fragments (r12-verbatim)
    auto gemms = [&](const int hn, const bf16x8* pf) {
        f32x4 vacc[4] = { {0.f,0.f,0.f,0.f}, {0.f,0.f,0.f,0.f}, {0.f,0.f,0.f,0.f}, {0.f,0.f,0.f,0.f} };
#pragma unroll
        for (int kt = 0; kt < 4; ++kt) {
#pragma unroll
            for (int ct = 0; ct < 4; ++ct) {
                const bf16x8 bb = *(const bf16x8*)&XTs[(ct * 16 + cq) * 128 + (((kt * 4 + rq) ^ cq) << 3)];
                vacc[ct] = __builtin_amdgcn_mfma_f32_16x16x32_bf16(pf[kt], bb, vacc[ct], 0, 0, 0);
            }
        }
#pragma unroll
        for (int ct = 0; ct < 4; ++ct)
#pragma unroll
            for (int rr = 0; rr < 4; ++rr)
                Vscr[w][rq * 4 + rr][ct * 16 + cq] = (bf16_t)vacc[ct][rr];
#pragma unroll
        for (int kt = 0; kt < 2; ++kt) {
            const bf16x8 a = *(const bf16x8*)&Vscr[w][cq][kt * 32 + rq * 8];
#pragma unroll
            for (int ct = 0; ct < 4; ++ct) {
                const bf16x8 bw = *(const bf16x8*)&WTall[hn * 4096 + (ct * 16 + cq) * 64 + (((kt * 4 + rq) ^ (cq & 7)) << 3)];
                oacc[ct] = __builtin_amdgcn_mfma_f32_16x16x32_bf16(a, bw, oacc[ct], 0, 0, 0);
            }
        }
    };

    // ---- 2-head pipelined loop: scores(h+1) VALU ∥ gemms(h) MFMA ----
    bf16x8 pA[4], pB[4];
    compute_pf(0, pA);
#pragma unroll 1
    for (int h = 0; h < NNH; h += 2) {
        compute_pf(h + 1, pB);      // VALU stream, independent of gemms(h)
        gemms(h, pA);               // MFMA stream — scheduler interleaves
        if (h + 2 < NNH) compute_pf(h + 2, pA);
        gemms(h + 1, pB);
    }

    // ---- epilogue: Out = oacc + bias (all 8 heads complete per wave) ----
#pragma unroll
    for (int ct = 0; ct < 4; ++ct) {
#pragma unroll
        for (int rr = 0; rr < 4; ++rr) {
            const int f = 16 * rt + rq * 4 + rr;
            const int o = ct * 16 + cq;
            Out[(((size_t)b * NF + f) * NT + t) * NDOUT + o] =
                oacc[ct][rr] + Bias[((size_t)f * NT + t) * NDOUT + o];
        }
    }
}

extern "C" void kernel_launch(void* const* d_in, const int* in_sizes, int n_in,
                              void* d_out, int out_size, void* d_ws, size_t ws_size,
                              hipStream_t stream) {
    (void)in_sizes; (void)n_in; (void)ws_size; (void)out_size;
    const float* X    = (const float*)d_in[0];
    const float* Wq   = (const float*)d_in[1];
    const float* Wk   = (const float*)d_in[2];
    const float* Wkey = (const float*)d_in[3];
    const float* U    = (const float*)d_in[4];
    const float* AC   = (const float*)d_in[5];
    const float* Al   = (const float*)d_in[6];
    // d_in[7] = R is analytic (delta^2, delta), folded into score formula
    const float* Wo   = (const float*)d_in[8];
    const float* Bias = (const float*)d_in[9];

    float* q_ws = (float*)d_ws;                       // 2 MB
    float* k_ws = q_ws + (size_t)NBS * NT * 16 * NF;  // 2 MB

    qk_project_kernel<<<dim3(NT * NF / 4), dim3(256), 0, stream>>>(X, Wq, Wk, q_ws, k_ws);
    spatial_attn_kernel<<<dim3(NBS * NT), dim3(512), 0, stream>>>(
        X, q_ws, k_ws, Wkey, U, AC, Al, Wo, Bias, (float*)d_out);
}

// Round 15
// 47.591 us; speedup vs baseline: 1.0976x; 1.0328x over previous
//
#include <hip/hip_runtime.h>
#include <hip/hip_bf16.h>

#define NBS 8
#define NT 32
#define NF 128
#define NDIN 64
#define NNH 8
#define NDOUT 64

typedef __bf16 bf16_t;
typedef __bf16 bf16x8 __attribute__((ext_vector_type(8)));
typedef float f32x4 __attribute__((ext_vector_type(4)));
typedef float f32x2 __attribute__((ext_vector_type(2)));

// ---------------- kernel 1: q/k projection ----------------
// One wave per (t,f): q[b,he] = sum_d X[b,f,t,d] * Wq[t,f,d,he], all 8 b at once.
// Wq/Wk/X each read exactly once from HBM -> ~46MB -> memory-bound, ~6us measured.
__global__ __launch_bounds__(256, 4)
void qk_project_kernel(const float* __restrict__ X,
                       const float* __restrict__ Wq,
                       const float* __restrict__ Wk,
                       float* __restrict__ q_ws,
                       float* __restrict__ k_ws)
{
    __shared__ float lx[4][8][64];
    const int w = threadIdx.x >> 6, lane = threadIdx.x & 63;
    const int gw = blockIdx.x * 4 + w;
    const int t = gw >> 7, f = gw & 127;

    {
        const int b = lane >> 3, d8 = (lane & 7) << 3;
        const float* src = &X[(((size_t)b * NF + f) * NT + t) * NDIN + d8];
        const float4 v0 = *(const float4*)src;
        const float4 v1 = *(const float4*)(src + 4);
        *(float4*)&lx[w][b][d8]     = v0;
        *(float4*)&lx[w][b][d8 + 4] = v1;
    }
    __syncthreads();

    const int dq = lane >> 4, he = lane & 15;
    const float* wq = Wq + ((size_t)t * NF + f) * (NDIN * 16);
    const float* wk = Wk + ((size_t)t * NF + f) * (NDIN * 16);
    float qa[8] = {0,0,0,0,0,0,0,0}, ka[8] = {0,0,0,0,0,0,0,0};
    for (int d0 = 0; d0 < NDIN; d0 += 4) {
        const int d = d0 + dq;
        const float wqv = wq[d * 16 + he];
        const float wkv = wk[d * 16 + he];
#pragma unroll
        for (int b = 0; b < 8; ++b) {
            const float x = lx[w][b][d];
            qa[b] = fmaf(x, wqv, qa[b]);
            ka[b] = fmaf(x, wkv, ka[b]);
        }
    }
#pragma unroll
    for (int b = 0; b < 8; ++b) {
        qa[b] += __shfl_xor(qa[b], 16); qa[b] += __shfl_xor(qa[b], 32);
        ka[b] += __shfl_xor(ka[b], 16); ka[b] += __shfl_xor(ka[b], 32);
    }
#pragma unroll
    for (int bb = 0; bb < 2; ++bb) {
        const int b = dq + bb * 4;
        q_ws[(((size_t)b * NT + t) * 16 + he) * NF + f] = qa[b];
        k_ws[(((size_t)b * NT + t) * 16 + he) * NF + f] = ka[b];
    }
}

// ---------------- kernel 2: attention + output GEMMs ----------------
// Base = r12 winner (49.0us total; r14 pipeline was neutral -> reverted).
// One block per (b,t), 512 thr = 8 waves, wave = row-tile, 8 heads/wave,
// ONE barrier. Round-15 deltas (LDS-pipe diet — r12 profile: ~720 LDS
// instrs/wave, ~46% of runtime on the LDS pipe at 2 waves/SIMD):
//  (1) XT fragments hoisted to 16 bf16x8 REGISTERS once (identical across
//      heads; was 16 reads x 8 heads = 128, now 16).
//  (2) u-pairs hoisted to 64 f32 registers once (u is h-independent; kvh
//      carries only k -> score reads halve: 32 -> 16 b128 per head).
// Register pressure is free here: grid = 256 = 1 block/CU, 2 waves/SIMD ->
// ~256-reg budget, no-spill to ~450 (m08). The 64-VGPR spill trap only
// triggers at launch-bounds >= 4 (r4/r5/r8); (512,2) is the proven bound.
__global__ __launch_bounds__(512, 2)
void spatial_attn_kernel(const float* __restrict__ X,
                         const float* __restrict__ q_ws,
                         const float* __restrict__ k_ws,
                         const float* __restrict__ Wkey,
                         const float* __restrict__ U,
                         const float* __restrict__ AC,
                         const float* __restrict__ Alpha,
                         const float* __restrict__ Wo,
                         const float* __restrict__ Bias,
                         float* __restrict__ Out)
{
    const int blk  = blockIdx.x;
    const int b    = blk & 7;
    const int t    = blk >> 3;
    const int tid  = threadIdx.x;
    const int w    = tid >> 6;
    const int lane = tid & 63;
    const int cq   = lane & 15;
    const int rq   = lane >> 4;
    const int rt   = w;                // row tile 0..7
    const int frow = 16 * rt + cq;

    // LDS carve: 124928 B (<= 160 KiB; grid caps at 1 block/CU anyway)
    __shared__ __align__(16) unsigned char smem[124928];
    bf16_t* XTs   = (bf16_t*)smem;                        // 16384: d*128 + (((f>>3)^(d&15))<<3) + (f&7)
    float*  kvh   = (float*)(smem + 16384);               //  8192: (h*64+P)*4 + {k0k0,k1k1}
    float*  kvu   = (float*)(smem + 24576);               //  1024: P*4 + {u0u0,u1u1}
    float4 (*qf)[128] = (float4 (*)[128])(smem + 25600);  // 16384: {q0,q1,kf0,kf1}(h,f)
    bf16_t* WTall = (bf16_t*)(smem + 41984);              // 65536: h*4096 + o*64 + (((d>>3)^(o&7))<<3) + (d&7)
    bf16_t (*Vscr)[16][68] = (bf16_t (*)[16][68])(smem + 107520); // 17408

    // ---- stage XT (X^T bf16, XOR-swizzled; r12-verbatim) ----
#pragma unroll
    for (int r = 0; r < 4; ++r) {
        const int idx = tid + r * 512;
        const int f = idx >> 4, d4 = (idx & 15) << 2;
        const float4 v = *(const float4*)&X[(((size_t)b * NF + f) * NT + t) * NDIN + d4];
        float vv[4]; vv[0] = v.x; vv[1] = v.y; vv[2] = v.z; vv[3] = v.w;
#pragma unroll
        for (int i = 0; i < 4; ++i) {
            const int d = d4 + i;
            XTs[d * 128 + (((f >> 3) ^ (d & 15)) << 3) + (f & 7)] = (bf16_t)vv[i];
        }
    }
    // ---- stage qf + kvh: one thread per (h,l), 2 reps (r13-verbatim) ----
#pragma unroll
    for (int r = 0; r < 2; ++r) {
        const int idx = tid + r * 512;
        const int hh = idx >> 7, l = idx & 127;
        const size_t qkb = ((size_t)b * NT + t) * 16;
        const float k0 = k_ws[(qkb + 2 * hh + 0) * NF + l];
        const float k1 = k_ws[(qkb + 2 * hh + 1) * NF + l];
        const float q0 = q_ws[(qkb + 2 * hh + 0) * NF + l];
        const float q1 = q_ws[(qkb + 2 * hh + 1) * NF + l];
        qf[hh][l] = make_float4(q0, q1, k0, k1);
        const int P = l >> 1, c = l & 1;
        const int base = (hh * 64 + P) * 4;
        kvh[base + 0 + c] = k0;
        kvh[base + 2 + c] = k1;
    }
    // ---- stage kvu (h-independent; r13-verbatim) ----
    if (tid < 128) {
        const int l = tid;
        const float2 u01 = *(const float2*)&U[((size_t)t * NF + l) * 2];
        const int P = l >> 1, c = l & 1;
        kvu[P * 4 + 0 + c] = u01.x;
        kvu[P * 4 + 2 + c] = u01.y;
    }
    // ---- stage WTall[h] (bf16, XOR-swizzled; r12-verbatim) ----
#pragma unroll
    for (int rep = 0; rep < 16; ++rep) {
        const int flat = rep * 512 + tid;              // 0..8191
        const int h = flat >> 10, f10 = flat & 1023;
        const int dd = f10 >> 4, o4 = (f10 & 15) << 2;
        const float4 v = *(const float4*)&Wo[((size_t)t * 512 + h * 64 + dd) * NDOUT + o4];
        float vv[4]; vv[0] = v.x; vv[1] = v.y; vv[2] = v.z; vv[3] = v.w;
#pragma unroll
        for (int i = 0; i < 4; ++i) {
            const int o = o4 + i;
            WTall[h * 4096 + o * 64 + (((dd >> 3) ^ (o & 7)) << 3) + (dd & 7)] = (bf16_t)vv[i];
        }
    }

    const float alpha_t = Alpha[t];
    const float wk00 = Wkey[t * 4 + 0], wk01 = Wkey[t * 4 + 1];
    const float wk10 = Wkey[t * 4 + 2], wk11 = Wkey[t * 4 + 3];

    __syncthreads();   // the ONLY barrier

    // ---- hoist 1: XT fragments -> registers (identical for all heads) ----
    bf16x8 xreg[4][4];
#pragma unroll
    for (int kt = 0; kt < 4; ++kt)
#pragma unroll
        for (int ct = 0; ct < 4; ++ct)
            xreg[kt][ct] = *(const bf16x8*)&XTs[(ct * 16 + cq) * 128 + (((kt * 4 + rq) ^ cq) << 3)];

    // ---- hoist 2: u-pairs -> registers (h-independent) ----
    f32x2 u0r[4][4], u1r[4][4];
#pragma unroll
    for (int kt = 0; kt < 4; ++kt)
#pragma unroll
        for (int j2 = 0; j2 < 4; ++j2) {
            const int P = kt * 16 + rq * 4 + j2;
            const float4 up = *(const float4*)&kvu[P * 4];
            u0r[kt][j2] = (f32x2){ up.x, up.y };
            u1r[kt][j2] = (f32x2){ up.z, up.w };
        }

    f32x4 oacc[4] = { {0.f,0.f,0.f,0.f}, {0.f,0.f,0.f,0.f}, {0.f,0.f,0.f,0.f}, {0.f,0.f,0.f,0.f} };

#pragma unroll 1
    for (int h = 0; h < NNH; ++h) {
        const float4 qq = qf[h][frow];             // {q0,q1,kf0,kf1}
        const float q0 = qq.x, q1 = qq.y, kf0 = qq.z, kf1 = qq.w;
        const float v1 = 2.f * alpha_t * AC[t * NNH + h];
        const float c0 = (q0 - alpha_t) * wk00 + (q1 + v1) * wk10;
        const float c1 = (q0 - alpha_t) * wk01 + (q1 + v1) * wk11;

        // ---- scores: k-pair from LDS (16 b128), u from registers ----
        f32x2 sc2[4][4];
        f32x2 mx2 = { -3.0e38f, -3.0e38f };
#pragma unroll
        for (int kt = 0; kt < 4; ++kt) {
#pragma unroll
            for (int j2 = 0; j2 < 4; ++j2) {
                const int P = kt * 16 + rq * 4 + j2;
                const float4 kp = *(const float4*)&kvh[(h * 64 + P) * 4];
                const f32x2 k0p = { kp.x, kp.y };
                const f32x2 k1p = { kp.z, kp.w };
                const float l0 = (float)(kt * 32 + rq * 8 + 2 * j2 - frow);
                const f32x2 delp = { l0, l0 + 1.f };
                f32x2 sv = k0p * q0 + k1p * q1 + u0r[kt][j2] * kf0 + u1r[kt][j2] * kf1
                         + (delp * c0 + c1) * delp;
                sc2[kt][j2] = sv;
                mx2 = __builtin_elementwise_max(mx2, sv);
            }
        }
        float rowmax = fmaxf(mx2.x, mx2.y);
        rowmax = fmaxf(rowmax, __shfl_xor(rowmax, 16));
        rowmax = fmaxf(rowmax, __shfl_xor(rowmax, 32));
        f32x2 s2 = { 0.f, 0.f };
#pragma unroll
        for (int kt = 0; kt < 4; ++kt)
#pragma unroll
            for (int j2 = 0; j2 < 4; ++j2) {
                f32x2 sv = sc2[kt][j2];
                const f32x2 e = { __expf(sv.x - rowmax), __expf(sv.y - rowmax) };
                s2 += e;
                sc2[kt][j2] = e;
            }
        float sum = s2.x + s2.y;
        sum += __shfl_xor(sum, 16);
        sum += __shfl_xor(sum, 32);
        const float rinv = 1.f / sum;

        // ---- GEMM1: V[16x64] = P[16x128] @ X[128x64]; B-frags from xreg ----
        f32x4 vacc[4] = { {0.f,0.f,0.f,0.f}, {0.f,0.f,0.f,0.f}, {0.f,0.f,0.f,0.f}, {0.f,0.f,0.f,0.f} };
#pragma unroll
        for (int kt = 0; kt < 4; ++kt) {
            bf16x8 pf;
#pragma unroll
            for (int j2 = 0; j2 < 4; ++j2) {
                const f32x2 e = sc2[kt][j2];
                pf[2 * j2 + 0] = (bf16_t)(e.x * rinv);
                pf[2 * j2 + 1] = (bf16_t)(e.y * rinv);
            }
#pragma unroll
            for (int ct = 0; ct < 4; ++ct)
                vacc[ct] = __builtin_amdgcn_mfma_f32_16x16x32_bf16(pf, xreg[kt][ct], vacc[ct], 0, 0, 0);
        }
        // V C-frags -> private wave scratch (intra-wave dep only, no barrier)
#pragma unroll
        for (int ct = 0; ct < 4; ++ct)
#pragma unroll
            for (int rr = 0; rr < 4; ++rr)
                Vscr[w][rq * 4 + rr][ct * 16 + cq] = (bf16_t)vacc[ct][rr];

        // ---- GEMM2: oacc += V[16x64] @ W_h[64x64] ----
#pragma unroll
        for (int kt = 0; kt < 2; ++kt) {
            const bf16x8 a = *(const bf16x8*)&Vscr[w][cq][kt * 32 + rq * 8];
#pragma unroll
            for (int ct = 0; ct < 4; ++ct) {
                const bf16x8 bw = *(const bf16x8*)&WTall[h * 4096 + (ct * 16 + cq) * 64 + (((kt * 4 + rq) ^ (cq & 7)) << 3)];
                oacc[ct] = __builtin_amdgcn_mfma_f32_16x16x32_bf16(a, bw, oacc[ct], 0, 0, 0);
            }
        }
    }

    // ---- epilogue: Out = oacc + bias (all 8 heads complete per wave) ----
#pragma unroll
    for (int ct = 0; ct < 4; ++ct) {
#pragma unroll
        for (int rr = 0; rr < 4; ++rr) {
            const int f = 16 * rt + rq * 4 + rr;
            const int o = ct * 16 + cq;
            Out[(((size_t)b * NF + f) * NT + t) * NDOUT + o] =
                oacc[ct][rr] + Bias[((size_t)f * NT + t) * NDOUT + o];
        }
    }
}

extern "C" void kernel_launch(void* const* d_in, const int* in_sizes, int n_in,
                              void* d_out, int out_size, void* d_ws, size_t ws_size,
                              hipStream_t stream) {
    (void)in_sizes; (void)n_in; (void)ws_size; (void)out_size;
    const float* X    = (const float*)d_in[0];
    const float* Wq   = (const float*)d_in[1];
    const float* Wk   = (const float*)d_in[2];
    const float* Wkey = (const float*)d_in[3];
    const float* U    = (const float*)d_in[4];
    const float* AC   = (const float*)d_in[5];
    const float* Al   = (const float*)d_in[6];
    // d_in[7] = R is analytic (delta^2, delta), folded into score formula
    const float* Wo   = (const float*)d_in[8];
    const float* Bias = (const float*)d_in[9];

    float* q_ws = (float*)d_ws;                       // 2 MB
    float* k_ws = q_ws + (size_t)NBS * NT * 16 * NF;  // 2 MB

    qk_project_kernel<<<dim3(NT * NF / 4), dim3(256), 0, stream>>>(X, Wq, Wk, q_ws, k_ws);
    spatial_attn_kernel<<<dim3(NBS * NT), dim3(512), 0, stream>>>(
        X, q_ws, k_ws, Wkey, U, AC, Al, Wo, Bias, (float*)d_out);
}